// Round 5
// baseline (335.268 us; speedup 1.0000x reference)
//
#include <hip/hip_runtime.h>
#include <hip/hip_bf16.h>

// ---------------------------------------------------------------------------
// MultiHeadAttention fused kernel for MI355X (gfx950)
// B=8 S=4096 Q=32 H=8 D=64 IN=512 NKV=1024
// detect dtype -> q projection (MFMA, 32 blocks) -> fused (merged K+V proj,
// single-barrier dbuf K-loop, LDS aliased to 80 KiB for 2 blocks/CU) -> div.
// ---------------------------------------------------------------------------

typedef float f32x4 __attribute__((ext_vector_type(4)));
typedef short s16x8 __attribute__((ext_vector_type(8)));
typedef short s16x4 __attribute__((ext_vector_type(4)));

__device__ __forceinline__ unsigned short f2bf(float f) {
  union { __hip_bfloat16 h; unsigned short u; } cv;
  cv.h = __float2bfloat16(f);
  return cv.u;
}
__device__ __forceinline__ float bf2f(unsigned short u) {
  union { unsigned short u; __hip_bfloat16 h; } cv;
  cv.u = u;
  return __bfloat162float(cv.h);
}
__device__ __forceinline__ float tofl(float v) { return v; }
__device__ __forceinline__ float tofl(__hip_bfloat16 v) { return __bfloat162float(v); }

__device__ __forceinline__ f32x4 mfma16(s16x8 a, s16x8 b, f32x4 c) {
  return __builtin_amdgcn_mfma_f32_16x16x32_bf16(a, b, c, 0, 0, 0);
}

// XOR swizzle in 8-u16 blocks over a 128-col row (breaks 256 B row stride).
__device__ __forceinline__ int sw_idx(int r, int c) {
  return r * 128 + ((((c >> 3) ^ (r & 7)) << 3) | (c & 7));
}

// 16-element (along K) register chunk, stored to LDS as bf16
template <typename T> struct RegChunk;
template <> struct RegChunk<float> {
  float4 v[4];
  __device__ __forceinline__ void load(const float* p) {
    const float4* q = reinterpret_cast<const float4*>(p);
    v[0] = q[0]; v[1] = q[1]; v[2] = q[2]; v[3] = q[3];
  }
  __device__ __forceinline__ void store(unsigned short* d) {
    union { unsigned short u[16]; s16x8 w[2]; } t;
    const float* f = reinterpret_cast<const float*>(v);
#pragma unroll
    for (int i = 0; i < 16; ++i) t.u[i] = f2bf(f[i]);
    reinterpret_cast<s16x8*>(d)[0] = t.w[0];
    reinterpret_cast<s16x8*>(d)[1] = t.w[1];
  }
};
template <> struct RegChunk<__hip_bfloat16> {
  s16x8 v[2];
  __device__ __forceinline__ void load(const __hip_bfloat16* p) {
    const s16x8* q = reinterpret_cast<const s16x8*>(p);
    v[0] = q[0]; v[1] = q[1];
  }
  __device__ __forceinline__ void store(unsigned short* d) {
    reinterpret_cast<s16x8*>(d)[0] = v[0];
    reinterpret_cast<s16x8*>(d)[1] = v[1];
  }
};

// ---------------------------------------------------------------------------
// dtype detection: EVEN u16 entries. bf16 array -> real bf16 values
// (plausible exponent ~100%); fp32 array (LE) -> mantissa low halves (~12%).
// flag: 1 = fp32, 0 = bf16.
// ---------------------------------------------------------------------------
__global__ void k_detect(const unsigned short* __restrict__ in16, int* __restrict__ flag) {
  __shared__ int cnt;
  int t = threadIdx.x;
  if (t == 0) cnt = 0;
  __syncthreads();
  unsigned short v = in16[2 * t];
  int e = (v >> 7) & 0xFF;
  int ok = (e >= 100 && e <= 130) ? 1 : 0;
  atomicAdd(&cnt, ok);
  __syncthreads();
  if (t == 0) *flag = (cnt >= 128) ? 0 : 1;
}

// ---------------------------------------------------------------------------
// q projection MFMA GEMM: qws[256][512] = queries @ Wq^T + bq
// grid (4 Mtiles, 8 Ntiles) = 32 blocks, 256 thr, 64x64 tile, BK=64,
// single-barrier double-buffered staging.
// MFMA 16x16x32_bf16: A m=lane&15,k=quad*8+j ; B n=lane&15,k=quad*8+j ;
//                     D col=lane&15,row=quad*4+reg
// ---------------------------------------------------------------------------
template <typename T>
__device__ __forceinline__ void qproj_body(const T* __restrict__ queries,
                                           const T* __restrict__ Wq,
                                           const T* __restrict__ bq,
                                           unsigned short* __restrict__ qws,
                                           unsigned short* smem) {
  unsigned short* Ab[2] = {smem, smem + 4096};
  unsigned short* Bb[2] = {smem + 8192, smem + 12288};
  const int Mt = blockIdx.x, Nt = blockIdx.y;
  const int tid = threadIdx.x;
  const int w = tid >> 6, l = tid & 63;
  const int quad = l >> 4, l16 = l & 15;

  const int r_st = tid >> 2;          // 0..63
  const int kk_st = (tid & 3) * 16;   // 0,16,32,48
  const T* Asrc = queries + ((size_t)(Mt * 64 + r_st)) * 512 + kk_st;
  const T* Bsrc = Wq + ((size_t)(Nt * 64 + r_st)) * 512 + kk_st;

  const f32x4 zero4 = {0.f, 0.f, 0.f, 0.f};
  f32x4 acc[4];
#pragma unroll
  for (int j = 0; j < 4; ++j) acc[j] = zero4;

  RegChunk<T> ra, rb;
  ra.load(Asrc);
  rb.load(Bsrc);
  ra.store(&Ab[0][r_st * 64 + kk_st]);
  rb.store(&Bb[0][r_st * 64 + kk_st]);
  ra.load(Asrc + 64);
  rb.load(Bsrc + 64);
  __syncthreads();

  for (int k0 = 0; k0 < 512; k0 += 64) {
    const int cur = (k0 >> 6) & 1;
#pragma unroll
    for (int kk = 0; kk < 2; ++kk) {
      s16x8 af = *reinterpret_cast<const s16x8*>(
          &Ab[cur][(w * 16 + l16) * 64 + kk * 32 + quad * 8]);
#pragma unroll
      for (int j = 0; j < 4; ++j) {
        s16x8 bf = *reinterpret_cast<const s16x8*>(
            &Bb[cur][(j * 16 + l16) * 64 + kk * 32 + quad * 8]);
        acc[j] = mfma16(af, bf, acc[j]);
      }
    }
    if (k0 + 64 < 512) {
      ra.store(&Ab[1 - cur][r_st * 64 + kk_st]);
      rb.store(&Bb[1 - cur][r_st * 64 + kk_st]);
      if (k0 + 128 < 512) {
        ra.load(Asrc + k0 + 128);
        rb.load(Bsrc + k0 + 128);
      }
      __syncthreads();
    }
  }

#pragma unroll
  for (int j = 0; j < 4; ++j) {
    float bb = tofl(bq[Nt * 64 + j * 16 + l16]);
#pragma unroll
    for (int rg = 0; rg < 4; ++rg) {
      int row = Mt * 64 + w * 16 + quad * 4 + rg;
      int col = Nt * 64 + j * 16 + l16;
      qws[(size_t)row * 512 + col] = f2bf(acc[j][rg] + bb);
    }
  }
}

__global__ __launch_bounds__(256) void k_qproj(const void* queries, const void* Wq,
                                               const void* bq, unsigned short* qws,
                                               const int* __restrict__ flag) {
  __shared__ __align__(16) unsigned short smem[16384];  // 32 KiB
  if (*flag == 1)
    qproj_body<float>((const float*)queries, (const float*)Wq, (const float*)bq, qws, smem);
  else
    qproj_body<__hip_bfloat16>((const __hip_bfloat16*)queries, (const __hip_bfloat16*)Wq,
                               (const __hip_bfloat16*)bq, qws, smem);
}

// ---------------------------------------------------------------------------
// Fused kernel. Grid (32 s-tiles, 8 batches, 4 head-pairs), 512 threads.
// One K-loop computes K-block (waves 0-3) and V-block (waves 4-7) 128x128.
// LDS (80 KiB, 2 blocks/CU):
//   [0..16384)      vbuf   V [d][s] swizzled (persistent)       32 KiB
//   [16384..40960)  union: staging dbuf (Ab0,Ab1,Bb0,Bb1)       48 KiB
//                      ==  kvbuf (16384 u16) + Pbuf (8192 u16)
// ---------------------------------------------------------------------------
template <typename T>
__device__ __forceinline__ void fused_body(
    const T* __restrict__ inputs, const T* __restrict__ masks,
    const T* __restrict__ Wkv, const T* __restrict__ bkv,
    const unsigned short* __restrict__ qws,
    float* __restrict__ num, float* __restrict__ den,
    unsigned short* smem) {
  unsigned short* vbuf = smem;              // 16384 u16
  unsigned short* Ab[2] = {smem + 16384, smem + 20480};
  unsigned short* Bb[2] = {smem + 24576, smem + 32768};
  unsigned short* kvbuf = smem + 16384;     // aliases Ab0,Ab1,Bb0
  unsigned short* Pbuf = smem + 32768;      // aliases Bb1

  const int stile = blockIdx.x;  // 0..31
  const int b = blockIdx.y;      // 0..7
  const int hp = blockIdx.z;     // 0..3
  const int s0 = stile * 128;
  const int tid = threadIdx.x;
  const int w = tid >> 6;        // 0..7
  const int l = tid & 63;
  const int quad = l >> 4;
  const int l16 = l & 15;
  const int which = w >> 2;              // 0 = K output, 1 = V output
  const int wr = ((w >> 1) & 1) * 64;
  const int wc = (w & 1) * 64;

  const f32x4 zero4 = {0.f, 0.f, 0.f, 0.f};
  f32x4 acc[4][4];
#pragma unroll
  for (int i = 0; i < 4; ++i)
#pragma unroll
    for (int j = 0; j < 4; ++j) acc[i][j] = zero4;

  // staging roles: tid<256 stage A (128 rows x 32), tid>=256 stage B (256 x 32)
  const int is_a = (tid < 256) ? 1 : 0;
  const int r_st = is_a ? (tid >> 1) : 0;
  const int kk_st = is_a ? ((tid & 1) * 16) : 0;
  const int u_st = tid - 256;  // 0..255 for B stagers
  const T* Asrc = inputs + ((size_t)(b * 4096 + s0 + r_st)) * 512 + kk_st;
  const int gr = (u_st < 128) ? (hp * 128 + u_st) : (512 + hp * 128 + (u_st - 128));
  const T* Bsrc = Wkv + ((size_t)(is_a ? 0 : gr)) * 512;

  RegChunk<T> ra, rb0, rb1;
  if (is_a) {
    ra.load(Asrc);
  } else {
    rb0.load(Bsrc);
    rb1.load(Bsrc + 16);
  }
  // store chunk 0 into buf 0, prefetch chunk 1
  if (is_a) {
    ra.store(&Ab[0][r_st * 32 + kk_st]);
    ra.load(Asrc + 32);
  } else {
    rb0.store(&Bb[0][u_st * 32]);
    rb1.store(&Bb[0][u_st * 32 + 16]);
    rb0.load(Bsrc + 32);
    rb1.load(Bsrc + 48);
  }
  __syncthreads();

  for (int k0 = 0; k0 < 512; k0 += 32) {
    const int cur = (k0 >> 5) & 1;
    s16x8 af[4], bfr[4];
#pragma unroll
    for (int i = 0; i < 4; ++i)
      af[i] = *reinterpret_cast<const s16x8*>(
          &Ab[cur][(wr + i * 16 + l16) * 32 + quad * 8]);
#pragma unroll
    for (int j = 0; j < 4; ++j)
      bfr[j] = *reinterpret_cast<const s16x8*>(
          &Bb[cur][(which * 128 + wc + j * 16 + l16) * 32 + quad * 8]);
#pragma unroll
    for (int i = 0; i < 4; ++i)
#pragma unroll
      for (int j = 0; j < 4; ++j) acc[i][j] = mfma16(af[i], bfr[j], acc[i][j]);

    if (k0 + 32 < 512) {
      // store prefetched chunk (k0+32) into the other buffer; MFMAs above
      // already issued, so the vmcnt wait here is overlapped.
      if (is_a) {
        ra.store(&Ab[1 - cur][r_st * 32 + kk_st]);
        if (k0 + 64 < 512) ra.load(Asrc + k0 + 64);
      } else {
        rb0.store(&Bb[1 - cur][u_st * 32]);
        rb1.store(&Bb[1 - cur][u_st * 32 + 16]);
        if (k0 + 64 < 512) {
          rb0.load(Bsrc + k0 + 64);
          rb1.load(Bsrc + k0 + 80);
        }
      }
      __syncthreads();
    }
  }
  __syncthreads();  // all staging reads done before kvbuf alias is written

  // spill acc(+bias): K -> kvbuf [s][c] (scalar, swizzled);
  //                   V -> vbuf [c=d][s] transposed (b64-packed, swizzled)
#pragma unroll
  for (int j = 0; j < 4; ++j) {
    float bb = tofl(bkv[which * 512 + hp * 128 + wc + j * 16 + l16]);
    if (which == 0) {
#pragma unroll
      for (int i = 0; i < 4; ++i)
#pragma unroll
        for (int rg = 0; rg < 4; ++rg) {
          int sl = wr + i * 16 + quad * 4 + rg;
          int c = wc + j * 16 + l16;
          kvbuf[sw_idx(sl, c)] = f2bf(acc[i][j][rg] + bb);
        }
    } else {
#pragma unroll
      for (int i = 0; i < 4; ++i) {
        s16x4 pk;
#pragma unroll
        for (int rg = 0; rg < 4; ++rg) pk[rg] = (short)f2bf(acc[i][j][rg] + bb);
        int crow = wc + j * 16 + l16;       // d index
        int scol = wr + i * 16 + quad * 4;  // s base (4-aligned, within 8-blk)
        *reinterpret_cast<s16x4*>(&vbuf[sw_idx(crow, scol)]) = pk;
      }
    }
  }
  __syncthreads();

  // ---- u-GEMM: u[2h][32q][128s]; wave -> (hh, mt, s-half) ----
  const int hh = w >> 2, mt = (w >> 1) & 1, sh = w & 1;
  {
    f32x4 ua[4];
#pragma unroll
    for (int j = 0; j < 4; ++j) ua[j] = zero4;
#pragma unroll
    for (int kk = 0; kk < 2; ++kk) {
      s16x8 aq = *reinterpret_cast<const s16x8*>(
          qws + ((size_t)(b * 32 + mt * 16 + l16)) * 512 + hp * 128 + hh * 64 + kk * 32 +
          quad * 8);
#pragma unroll
      for (int j = 0; j < 4; ++j) {
        s16x8 bk = *reinterpret_cast<const s16x8*>(
            &kvbuf[sw_idx(sh * 64 + j * 16 + l16, hh * 64 + kk * 32 + quad * 8)]);
        ua[j] = mfma16(aq, bk, ua[j]);
      }
    }
    const float scale = 0.044194173824159216f;  // 1/sqrt(512)
    float dsum[4] = {0.f, 0.f, 0.f, 0.f};
#pragma unroll
    for (int j = 0; j < 4; ++j) {
      int scol = sh * 64 + j * 16 + l16;
      float mask = tofl(masks[(size_t)b * 4096 + s0 + scol]);
#pragma unroll
      for (int rg = 0; rg < 4; ++rg) {
        int qrow = mt * 16 + quad * 4 + rg;
        float uv = ua[j][rg] * scale;
        float e = uv > 0.f ? uv : expm1f(uv);
        e = fminf(fmaxf(e, -15.f), 15.f);
        float p = expf(e) * mask;
        unsigned short pu = f2bf(p);
        Pbuf[sw_idx(hh * 32 + qrow, scol)] = pu;
        dsum[rg] += bf2f(pu);  // sum the ROUNDED value num-GEMM will use
      }
    }
#pragma unroll
    for (int rg = 0; rg < 4; ++rg) {
      float s = dsum[rg];
      s += __shfl_xor(s, 1);
      s += __shfl_xor(s, 2);
      s += __shfl_xor(s, 4);
      s += __shfl_xor(s, 8);
      if (l16 == 0) {
        int qrow = mt * 16 + quad * 4 + rg;
        atomicAdd(&den[((size_t)(b * 32 + qrow)) * 8 + hp * 2 + hh], s);
      }
    }
  }
  __syncthreads();  // Pbuf complete; kvbuf reads done

  // ---- num-GEMM: num[2h][32q][64d]; wave -> (hh, mt, d-half) ----
  {
    const int dh = w & 1;
    f32x4 na[2];
    na[0] = zero4;
    na[1] = zero4;
#pragma unroll
    for (int kk = 0; kk < 4; ++kk) {
      s16x8 ap = *reinterpret_cast<const s16x8*>(
          &Pbuf[sw_idx(hh * 32 + mt * 16 + l16, kk * 32 + quad * 8)]);
#pragma unroll
      for (int jj = 0; jj < 2; ++jj) {
        int j = dh * 2 + jj;
        s16x8 bv = *reinterpret_cast<const s16x8*>(
            &vbuf[sw_idx(hh * 64 + j * 16 + l16, kk * 32 + quad * 8)]);
        na[jj] = mfma16(ap, bv, na[jj]);
      }
    }
    const int h = hp * 2 + hh;
#pragma unroll
    for (int jj = 0; jj < 2; ++jj) {
      int d = (dh * 2 + jj) * 16 + l16;
#pragma unroll
      for (int rg = 0; rg < 4; ++rg) {
        int qrow = mt * 16 + quad * 4 + rg;
        atomicAdd(&num[(((size_t)(b * 32 + qrow)) * 8 + h) * 64 + d], na[jj][rg]);
      }
    }
  }
}

__global__ __launch_bounds__(512, 4) void k_fused(const void* inputs, const void* masks,
                                                  const void* Wkv, const void* bkv,
                                                  const unsigned short* __restrict__ qws,
                                                  float* __restrict__ num,
                                                  float* __restrict__ den,
                                                  const int* __restrict__ flag) {
  __shared__ __align__(16) unsigned short smem[40960];  // 80 KiB
  if (*flag == 1)
    fused_body<float>((const float*)inputs, (const float*)masks, (const float*)Wkv,
                      (const float*)bkv, qws, num, den, smem);
  else
    fused_body<__hip_bfloat16>((const __hip_bfloat16*)inputs, (const __hip_bfloat16*)masks,
                               (const __hip_bfloat16*)Wkv, (const __hip_bfloat16*)bkv, qws,
                               num, den, smem);
}

// ---------------------------------------------------------------------------
__global__ __launch_bounds__(256) void k_div(const float* __restrict__ num,
                                             const float* __restrict__ den, void* out,
                                             const int* __restrict__ flag) {
  int i = blockIdx.x * 256 + threadIdx.x;
  float v = num[i] / den[i >> 6];
  if (*flag == 1)
    ((float*)out)[i] = v;
  else
    ((__hip_bfloat16*)out)[i] = __float2bfloat16(v);
}

// ---------------------------------------------------------------------------
extern "C" void kernel_launch(void* const* d_in, const int* in_sizes, int n_in,
                              void* d_out, int out_size, void* d_ws, size_t ws_size,
                              hipStream_t stream) {
  // d_in: 0 inputs, 1 queries, 2 masks, 3 Wkv, 4 bkv, 5 Wq, 6 bq
  // ws: [0] flag ; [1024] den 2048 f32 ; [16384] num 131072 f32 ;
  //     [540672] qws 131072 u16 -> 802816 bytes
  if (ws_size < 802816) return;
  char* ws = (char*)d_ws;
  int* flag = (int*)ws;
  float* den = (float*)(ws + 1024);
  float* num = (float*)(ws + 16384);
  unsigned short* qws = (unsigned short*)(ws + 540672);

  hipMemsetAsync(d_ws, 0, 540672, stream);

  k_detect<<<1, 256, 0, stream>>>((const unsigned short*)d_in[0], flag);

  dim3 gq(4, 8);
  k_qproj<<<gq, 256, 0, stream>>>(d_in[1], d_in[5], d_in[6], qws, flag);

  dim3 g2(32, 8, 4);
  k_fused<<<g2, 512, 0, stream>>>(d_in[0], d_in[2], d_in[3], d_in[4], qws, num, den, flag);

  k_div<<<512, 256, 0, stream>>>(num, den, d_out, flag);
}

// Round 6
// 264.184 us; speedup vs baseline: 1.2691x; 1.2691x over previous
//
#include <hip/hip_runtime.h>
#include <hip/hip_bf16.h>

// ---------------------------------------------------------------------------
// MultiHeadAttention fused kernel for MI355X (gfx950)
// B=8 S=4096 Q=32 H=8 D=64 IN=512 NKV=1024
// detect dtype -> q projection (MFMA, 32 blocks) -> fused (merged K+V proj,
// single-barrier dbuf K-loop, 1024 thr / 16 waves, acc 32 AGPR/wave,
// stride-40 staging for bank balance) -> divide.
// R6: fix R5 spill regression (launch_bounds cap vs 64-reg acc) by shrinking
//     per-wave tile to 64x32; balance staging banks with padded stride.
// ---------------------------------------------------------------------------

typedef float f32x4 __attribute__((ext_vector_type(4)));
typedef short s16x8 __attribute__((ext_vector_type(8)));
typedef short s16x4 __attribute__((ext_vector_type(4)));

#define STG 40  // staging row stride in u16 (80 B -> bank advance 20, balanced)

__device__ __forceinline__ unsigned short f2bf(float f) {
  union { __hip_bfloat16 h; unsigned short u; } cv;
  cv.h = __float2bfloat16(f);
  return cv.u;
}
__device__ __forceinline__ float bf2f(unsigned short u) {
  union { unsigned short u; __hip_bfloat16 h; } cv;
  cv.u = u;
  return __bfloat162float(cv.h);
}
__device__ __forceinline__ float tofl(float v) { return v; }
__device__ __forceinline__ float tofl(__hip_bfloat16 v) { return __bfloat162float(v); }

__device__ __forceinline__ f32x4 mfma16(s16x8 a, s16x8 b, f32x4 c) {
  return __builtin_amdgcn_mfma_f32_16x16x32_bf16(a, b, c, 0, 0, 0);
}

// XOR swizzle in 8-u16 blocks over a 128-col row (breaks 256 B row stride).
__device__ __forceinline__ int sw_idx(int r, int c) {
  return r * 128 + ((((c >> 3) ^ (r & 7)) << 3) | (c & 7));
}

// 16-element register chunk (B stagers)
template <typename T> struct RegChunk;
template <> struct RegChunk<float> {
  float4 v[4];
  __device__ __forceinline__ void load(const float* p) {
    const float4* q = reinterpret_cast<const float4*>(p);
    v[0] = q[0]; v[1] = q[1]; v[2] = q[2]; v[3] = q[3];
  }
  __device__ __forceinline__ void store(unsigned short* d) {
    union { unsigned short u[16]; s16x8 w[2]; } t;
    const float* f = reinterpret_cast<const float*>(v);
#pragma unroll
    for (int i = 0; i < 16; ++i) t.u[i] = f2bf(f[i]);
    reinterpret_cast<s16x8*>(d)[0] = t.w[0];
    reinterpret_cast<s16x8*>(d)[1] = t.w[1];
  }
};
template <> struct RegChunk<__hip_bfloat16> {
  s16x8 v[2];
  __device__ __forceinline__ void load(const __hip_bfloat16* p) {
    const s16x8* q = reinterpret_cast<const s16x8*>(p);
    v[0] = q[0]; v[1] = q[1];
  }
  __device__ __forceinline__ void store(unsigned short* d) {
    reinterpret_cast<s16x8*>(d)[0] = v[0];
    reinterpret_cast<s16x8*>(d)[1] = v[1];
  }
};

// 8-element register chunk (A stagers)
template <typename T> struct RegChunk8;
template <> struct RegChunk8<float> {
  float4 v[2];
  __device__ __forceinline__ void load(const float* p) {
    const float4* q = reinterpret_cast<const float4*>(p);
    v[0] = q[0]; v[1] = q[1];
  }
  __device__ __forceinline__ void store(unsigned short* d) {
    union { unsigned short u[8]; s16x8 w; } t;
    const float* f = reinterpret_cast<const float*>(v);
#pragma unroll
    for (int i = 0; i < 8; ++i) t.u[i] = f2bf(f[i]);
    *reinterpret_cast<s16x8*>(d) = t.w;
  }
};
template <> struct RegChunk8<__hip_bfloat16> {
  s16x8 v;
  __device__ __forceinline__ void load(const __hip_bfloat16* p) {
    v = *reinterpret_cast<const s16x8*>(p);
  }
  __device__ __forceinline__ void store(unsigned short* d) {
    *reinterpret_cast<s16x8*>(d) = v;
  }
};

// ---------------------------------------------------------------------------
// dtype detection: EVEN u16 entries. bf16 array -> real bf16 values
// (plausible exponent ~100%); fp32 array (LE) -> mantissa low halves (~12%).
// flag: 1 = fp32, 0 = bf16.
// ---------------------------------------------------------------------------
__global__ void k_detect(const unsigned short* __restrict__ in16, int* __restrict__ flag) {
  __shared__ int cnt;
  int t = threadIdx.x;
  if (t == 0) cnt = 0;
  __syncthreads();
  unsigned short v = in16[2 * t];
  int e = (v >> 7) & 0xFF;
  int ok = (e >= 100 && e <= 130) ? 1 : 0;
  atomicAdd(&cnt, ok);
  __syncthreads();
  if (t == 0) *flag = (cnt >= 128) ? 0 : 1;
}

// ---------------------------------------------------------------------------
// q projection MFMA GEMM: qws[256][512] = queries @ Wq^T + bq
// grid (4,8) = 32 blocks, 256 thr, 64x64 tile, BK=64, single-barrier dbuf.
// MFMA 16x16x32_bf16: A m=lane&15,k=quad*8+j ; B n=lane&15,k=quad*8+j ;
//                     D col=lane&15,row=quad*4+reg
// ---------------------------------------------------------------------------
template <typename T>
__device__ __forceinline__ void qproj_body(const T* __restrict__ queries,
                                           const T* __restrict__ Wq,
                                           const T* __restrict__ bq,
                                           unsigned short* __restrict__ qws,
                                           unsigned short* smem) {
  unsigned short* Ab[2] = {smem, smem + 4096};
  unsigned short* Bb[2] = {smem + 8192, smem + 12288};
  const int Mt = blockIdx.x, Nt = blockIdx.y;
  const int tid = threadIdx.x;
  const int w = tid >> 6, l = tid & 63;
  const int quad = l >> 4, l16 = l & 15;

  const int r_st = tid >> 2;          // 0..63
  const int kk_st = (tid & 3) * 16;   // 0,16,32,48
  const T* Asrc = queries + ((size_t)(Mt * 64 + r_st)) * 512 + kk_st;
  const T* Bsrc = Wq + ((size_t)(Nt * 64 + r_st)) * 512 + kk_st;

  const f32x4 zero4 = {0.f, 0.f, 0.f, 0.f};
  f32x4 acc[4];
#pragma unroll
  for (int j = 0; j < 4; ++j) acc[j] = zero4;

  RegChunk<T> ra, rb;
  ra.load(Asrc);
  rb.load(Bsrc);
  ra.store(&Ab[0][r_st * 64 + kk_st]);
  rb.store(&Bb[0][r_st * 64 + kk_st]);
  ra.load(Asrc + 64);
  rb.load(Bsrc + 64);
  __syncthreads();

  for (int k0 = 0; k0 < 512; k0 += 64) {
    const int cur = (k0 >> 6) & 1;
#pragma unroll
    for (int kk = 0; kk < 2; ++kk) {
      s16x8 af = *reinterpret_cast<const s16x8*>(
          &Ab[cur][(w * 16 + l16) * 64 + kk * 32 + quad * 8]);
#pragma unroll
      for (int j = 0; j < 4; ++j) {
        s16x8 bf = *reinterpret_cast<const s16x8*>(
            &Bb[cur][(j * 16 + l16) * 64 + kk * 32 + quad * 8]);
        acc[j] = mfma16(af, bf, acc[j]);
      }
    }
    if (k0 + 64 < 512) {
      ra.store(&Ab[1 - cur][r_st * 64 + kk_st]);
      rb.store(&Bb[1 - cur][r_st * 64 + kk_st]);
      if (k0 + 128 < 512) {
        ra.load(Asrc + k0 + 128);
        rb.load(Bsrc + k0 + 128);
      }
      __syncthreads();
    }
  }

#pragma unroll
  for (int j = 0; j < 4; ++j) {
    float bb = tofl(bq[Nt * 64 + j * 16 + l16]);
#pragma unroll
    for (int rg = 0; rg < 4; ++rg) {
      int row = Mt * 64 + w * 16 + quad * 4 + rg;
      int col = Nt * 64 + j * 16 + l16;
      qws[(size_t)row * 512 + col] = f2bf(acc[j][rg] + bb);
    }
  }
}

__global__ __launch_bounds__(256) void k_qproj(const void* queries, const void* Wq,
                                               const void* bq, unsigned short* qws,
                                               const int* __restrict__ flag) {
  __shared__ __align__(16) unsigned short smem[16384];  // 32 KiB
  if (*flag == 1)
    qproj_body<float>((const float*)queries, (const float*)Wq, (const float*)bq, qws, smem);
  else
    qproj_body<__hip_bfloat16>((const __hip_bfloat16*)queries, (const __hip_bfloat16*)Wq,
                               (const __hip_bfloat16*)bq, qws, smem);
}

// ---------------------------------------------------------------------------
// Fused kernel. Grid (32 s-tiles, 8 batches, 4 head-pairs), 1024 threads
// (16 waves, 4/SIMD). One K-loop computes K-block (waves 0-7) and V-block
// (waves 8-15), each wave a 64x32 quadrant (acc[4][2] = 32 AGPR).
// LDS (92 KiB):
//   [0..16384)      vbuf   V [d][s] swizzled (persistent)        32 KiB
//   [16384..47104)  staging dbuf, stride-40 rows:
//                     Ab0 @16384(5120) Ab1 @21504 Bb0 @26624(10240) Bb1 @36864
//                   aliased after K-loop by kvbuf(16384) + Pbuf(8192)
// ---------------------------------------------------------------------------
template <typename T>
__device__ __forceinline__ void fused_body(
    const T* __restrict__ inputs, const T* __restrict__ masks,
    const T* __restrict__ Wkv, const T* __restrict__ bkv,
    const unsigned short* __restrict__ qws,
    float* __restrict__ num, float* __restrict__ den,
    unsigned short* smem) {
  unsigned short* vbuf = smem;  // 16384 u16
  unsigned short* Ab[2] = {smem + 16384, smem + 21504};
  unsigned short* Bb[2] = {smem + 26624, smem + 36864};
  unsigned short* kvbuf = smem + 16384;  // K [s][c] swizzled, 16384 u16
  unsigned short* Pbuf = smem + 32768;   // P [2h*32q][s] swizzled, 8192 u16

  const int stile = blockIdx.x;  // 0..31
  const int b = blockIdx.y;      // 0..7
  const int hp = blockIdx.z;     // 0..3
  const int s0 = stile * 128;
  const int tid = threadIdx.x;
  const int w = tid >> 6;        // 0..15
  const int l = tid & 63;
  const int quad = l >> 4;
  const int l16 = l & 15;
  const int which = w >> 3;             // 0 = K output, 1 = V output
  const int sub = w & 7;
  const int wr = (sub >> 2) * 64;       // row group (2 x 64)
  const int wc = (sub & 3) * 32;        // col group (4 x 32)

  const f32x4 zero4 = {0.f, 0.f, 0.f, 0.f};
  f32x4 acc[4][2];
#pragma unroll
  for (int i = 0; i < 4; ++i)
#pragma unroll
    for (int j = 0; j < 2; ++j) acc[i][j] = zero4;

  // staging: waves 0-7 stage A (128 x 32, 1 granule/lane),
  //          waves 8-15 stage B (256 x 32, 2 granules/lane)
  const int is_a = (tid < 512) ? 1 : 0;
  const int row_a = tid >> 2;          // 0..127
  const int qg_a = (tid & 3) * 8;      // granule col offset in u16
  const int u_b = tid - 512;           // 0..511
  const int row_b = u_b >> 1;          // 0..255
  const int half_b = (u_b & 1) * 16;   // 0 or 16
  const T* Asrc = inputs + ((size_t)(b * 4096 + s0 + row_a)) * 512 + qg_a;
  const int gr = (row_b < 128) ? (hp * 128 + row_b) : (512 + hp * 128 + (row_b - 128));
  const T* Bsrc = Wkv + ((size_t)(is_a ? 0 : gr)) * 512 + half_b;

  RegChunk8<T> ra;
  RegChunk<T> rb;
  if (is_a) {
    ra.load(Asrc);
    ra.store(&Ab[0][row_a * STG + qg_a]);
    ra.load(Asrc + 32);
  } else {
    rb.load(Bsrc);
    rb.store(&Bb[0][row_b * STG + half_b]);
    rb.load(Bsrc + 32);
  }
  __syncthreads();

  for (int k0 = 0; k0 < 512; k0 += 32) {
    const int cur = (k0 >> 5) & 1;
    s16x8 af[4], bfr[2];
#pragma unroll
    for (int i = 0; i < 4; ++i)
      af[i] = *reinterpret_cast<const s16x8*>(
          &Ab[cur][(wr + i * 16 + l16) * STG + quad * 8]);
#pragma unroll
    for (int j = 0; j < 2; ++j)
      bfr[j] = *reinterpret_cast<const s16x8*>(
          &Bb[cur][(which * 128 + wc + j * 16 + l16) * STG + quad * 8]);
#pragma unroll
    for (int i = 0; i < 4; ++i)
#pragma unroll
      for (int j = 0; j < 2; ++j) acc[i][j] = mfma16(af[i], bfr[j], acc[i][j]);

    if (k0 + 32 < 512) {
      if (is_a) {
        ra.store(&Ab[1 - cur][row_a * STG + qg_a]);
        if (k0 + 64 < 512) ra.load(Asrc + k0 + 64);
      } else {
        rb.store(&Bb[1 - cur][row_b * STG + half_b]);
        if (k0 + 64 < 512) rb.load(Bsrc + k0 + 64);
      }
      __syncthreads();
    }
  }
  __syncthreads();  // staging reads done before kvbuf alias is written

  // spill acc(+bias): K -> kvbuf [s][c] scalar; V -> vbuf [c=d][s] b64-packed
#pragma unroll
  for (int j = 0; j < 2; ++j) {
    float bb = tofl(bkv[which * 512 + hp * 128 + wc + j * 16 + l16]);
    if (which == 0) {
#pragma unroll
      for (int i = 0; i < 4; ++i)
#pragma unroll
        for (int rg = 0; rg < 4; ++rg) {
          int sl = wr + i * 16 + quad * 4 + rg;
          int c = wc + j * 16 + l16;
          kvbuf[sw_idx(sl, c)] = f2bf(acc[i][j][rg] + bb);
        }
    } else {
#pragma unroll
      for (int i = 0; i < 4; ++i) {
        s16x4 pk;
#pragma unroll
        for (int rg = 0; rg < 4; ++rg) pk[rg] = (short)f2bf(acc[i][j][rg] + bb);
        int crow = wc + j * 16 + l16;       // d index
        int scol = wr + i * 16 + quad * 4;  // s base (4-aligned within 8-blk)
        *reinterpret_cast<s16x4*>(&vbuf[sw_idx(crow, scol)]) = pk;
      }
    }
  }
  __syncthreads();

  // ---- u-GEMM: u[2h][32q][128s]; wave -> (hh, mt, sj: 32 s-cols) ----
  const int hh = w >> 3, mt = (w >> 2) & 1, sj = w & 3;
  {
    f32x4 ua[2];
    ua[0] = zero4;
    ua[1] = zero4;
#pragma unroll
    for (int kk = 0; kk < 2; ++kk) {
      s16x8 aq = *reinterpret_cast<const s16x8*>(
          qws + ((size_t)(b * 32 + mt * 16 + l16)) * 512 + hp * 128 + hh * 64 + kk * 32 +
          quad * 8);
#pragma unroll
      for (int j = 0; j < 2; ++j) {
        s16x8 bk = *reinterpret_cast<const s16x8*>(
            &kvbuf[sw_idx(sj * 32 + j * 16 + l16, hh * 64 + kk * 32 + quad * 8)]);
        ua[j] = mfma16(aq, bk, ua[j]);
      }
    }
    const float scale = 0.044194173824159216f;  // 1/sqrt(512)
    float dsum[4] = {0.f, 0.f, 0.f, 0.f};
#pragma unroll
    for (int j = 0; j < 2; ++j) {
      int scol = sj * 32 + j * 16 + l16;
      float mask = tofl(masks[(size_t)b * 4096 + s0 + scol]);
#pragma unroll
      for (int rg = 0; rg < 4; ++rg) {
        int qrow = mt * 16 + quad * 4 + rg;
        float uv = ua[j][rg] * scale;
        float e = uv > 0.f ? uv : expm1f(uv);
        e = fminf(fmaxf(e, -15.f), 15.f);
        float p = expf(e) * mask;
        unsigned short pu = f2bf(p);
        Pbuf[sw_idx(hh * 32 + qrow, scol)] = pu;
        dsum[rg] += bf2f(pu);  // sum the ROUNDED value num-GEMM will use
      }
    }
#pragma unroll
    for (int rg = 0; rg < 4; ++rg) {
      float s = dsum[rg];
      s += __shfl_xor(s, 1);
      s += __shfl_xor(s, 2);
      s += __shfl_xor(s, 4);
      s += __shfl_xor(s, 8);
      if (l16 == 0) {
        int qrow = mt * 16 + quad * 4 + rg;
        atomicAdd(&den[((size_t)(b * 32 + qrow)) * 8 + hp * 2 + hh], s);
      }
    }
  }
  __syncthreads();  // Pbuf complete; kvbuf reads done

  // ---- num-GEMM: num[2h][32q][64d]; wave -> (hh, mt, dj) one 16x16 tile ----
  {
    const int dj = w & 3;
    f32x4 na = zero4;
#pragma unroll
    for (int kk = 0; kk < 4; ++kk) {
      s16x8 ap = *reinterpret_cast<const s16x8*>(
          &Pbuf[sw_idx(hh * 32 + mt * 16 + l16, kk * 32 + quad * 8)]);
      s16x8 bv = *reinterpret_cast<const s16x8*>(
          &vbuf[sw_idx(hh * 64 + dj * 16 + l16, kk * 32 + quad * 8)]);
      na = mfma16(ap, bv, na);
    }
    const int h = hp * 2 + hh;
    const int d = dj * 16 + l16;
#pragma unroll
    for (int rg = 0; rg < 4; ++rg) {
      int qrow = mt * 16 + quad * 4 + rg;
      atomicAdd(&num[(((size_t)(b * 32 + qrow)) * 8 + h) * 64 + d], na[rg]);
    }
  }
}

__global__ __launch_bounds__(1024, 4) void k_fused(const void* inputs, const void* masks,
                                                   const void* Wkv, const void* bkv,
                                                   const unsigned short* __restrict__ qws,
                                                   float* __restrict__ num,
                                                   float* __restrict__ den,
                                                   const int* __restrict__ flag) {
  __shared__ __align__(16) unsigned short smem[47104];  // 92 KiB
  if (*flag == 1)
    fused_body<float>((const float*)inputs, (const float*)masks, (const float*)Wkv,
                      (const float*)bkv, qws, num, den, smem);
  else
    fused_body<__hip_bfloat16>((const __hip_bfloat16*)inputs, (const __hip_bfloat16*)masks,
                               (const __hip_bfloat16*)Wkv, (const __hip_bfloat16*)bkv, qws,
                               num, den, smem);
}

// ---------------------------------------------------------------------------
__global__ __launch_bounds__(256) void k_div(const float* __restrict__ num,
                                             const float* __restrict__ den, void* out,
                                             const int* __restrict__ flag) {
  int i = blockIdx.x * 256 + threadIdx.x;
  float v = num[i] / den[i >> 6];
  if (*flag == 1)
    ((float*)out)[i] = v;
  else
    ((__hip_bfloat16*)out)[i] = __float2bfloat16(v);
}

// ---------------------------------------------------------------------------
extern "C" void kernel_launch(void* const* d_in, const int* in_sizes, int n_in,
                              void* d_out, int out_size, void* d_ws, size_t ws_size,
                              hipStream_t stream) {
  // d_in: 0 inputs, 1 queries, 2 masks, 3 Wkv, 4 bkv, 5 Wq, 6 bq
  // ws: [0] flag ; [1024] den 2048 f32 ; [16384] num 131072 f32 ;
  //     [540672] qws 131072 u16 -> 802816 bytes
  if (ws_size < 802816) return;
  char* ws = (char*)d_ws;
  int* flag = (int*)ws;
  float* den = (float*)(ws + 1024);
  float* num = (float*)(ws + 16384);
  unsigned short* qws = (unsigned short*)(ws + 540672);

  hipMemsetAsync(d_ws, 0, 540672, stream);

  k_detect<<<1, 256, 0, stream>>>((const unsigned short*)d_in[0], flag);

  dim3 gq(4, 8);
  k_qproj<<<gq, 256, 0, stream>>>(d_in[1], d_in[5], d_in[6], qws, flag);

  dim3 g2(32, 8, 4);
  k_fused<<<g2, 1024, 0, stream>>>(d_in[0], d_in[2], d_in[3], d_in[4], qws, num, den, flag);

  k_div<<<512, 256, 0, stream>>>(num, den, d_out, flag);
}